// Round 4
// baseline (221.579 us; speedup 1.0000x reference)
//
#include <hip/hip_runtime.h>
#include <hip/hip_bf16.h>
#include <cstdint>
#include <cmath>

#define DIMC   192
#define DSTATE 16
#define DCONV  4
#define DINNER 384
#define DTRANK 12
#define BSZ    4
#define HSP    64
#define WSP    64
#define LSEQ   4096
#define NTOK   (BSZ*LSEQ)            // 16384
#define XPN    (DTRANK + 2*DSTATE)   // 44
#define XZW    (2*DINNER)            // 768
#define LC3    32                    // scan chunk length
#define NCH3   (LSEQ/LC3)            // 128 chunks per batch
#define NST3   ((size_t)BSZ*NCH3*DINNER*DSTATE)  // 3,145,728 floats per state array

typedef unsigned short ushortT;
using short8 = __attribute__((ext_vector_type(8))) short;
using f32x4  = __attribute__((ext_vector_type(4))) float;

// ---------------------------------------------------------------------------
// K0: weight conversion f32 -> bf16. [in_proj 768x192][x_proj padded 48x384][out_proj 192x384]
// ---------------------------------------------------------------------------
__global__ __launch_bounds__(256) void wcvt_kernel(
    const float* __restrict__ w_in, const float* __restrict__ w_x,
    const float* __restrict__ w_out, __hip_bfloat16* __restrict__ wbf) {
  int gid = blockIdx.x * 256 + threadIdx.x;   // < 239616
  float v;
  if (gid < 147456) {
    v = w_in[gid];
  } else if (gid < 147456 + 18432) {
    int e = gid - 147456;
    int r = e / DINNER, c = e % DINNER;
    v = (r < 44) ? w_x[r * DINNER + c] : 0.f;   // rows 44..47 zero-pad
  } else {
    v = w_out[gid - 147456 - 18432];
  }
  wbf[gid] = __float2bfloat16(v);
}

// ---------------------------------------------------------------------------
// K1: [B,C,H,W] -> LayerNorm over C -> xn_bf16 [B*L, C]
// ---------------------------------------------------------------------------
__global__ __launch_bounds__(256) void ln_kernel(
    const float* __restrict__ x, const float* __restrict__ ln_w,
    const float* __restrict__ ln_b, __hip_bfloat16* __restrict__ xn) {
  __shared__ float xs[DIMC][WSP + 1];
  __shared__ float mu_s[WSP], rs_s[WSP];
  int bh = blockIdx.x;
  int b = bh >> 6, h = bh & 63;
  int tid = threadIdx.x;
  const float* xb = x + (size_t)b * DIMC * LSEQ + (size_t)h * WSP;
  for (int e = tid; e < DIMC * WSP; e += 256) {
    int c = e >> 6, w = e & 63;
    xs[c][w] = xb[(size_t)c * LSEQ + w];
  }
  __syncthreads();
  if (tid < WSP) {
    float s = 0.f, s2 = 0.f;
    for (int c = 0; c < DIMC; ++c) { float v = xs[c][tid]; s += v; s2 = fmaf(v, v, s2); }
    float mu = s * (1.f / DIMC);
    float var = s2 * (1.f / DIMC) - mu * mu;
    mu_s[tid] = mu;
    rs_s[tid] = rsqrtf(var + 1e-5f);
  }
  __syncthreads();
  __hip_bfloat16* xo = xn + (size_t)(b * LSEQ + h * WSP) * DIMC;
  for (int e = tid; e < DIMC * WSP; e += 256) {
    int w = e / DIMC, c = e % DIMC;
    xo[(size_t)w * DIMC + c] =
        __float2bfloat16((xs[c][w] - mu_s[w]) * rs_s[w] * ln_w[c] + ln_b[c]);
  }
}

// ---------------------------------------------------------------------------
// bf16 MFMA GEMM: C[M,N] = A[M,K] @ B[N,K]^T   (both row-major [dim][K] bf16)
// EPI 0: f32 out, guard n<Nreal.  EPI 1: per-batch residual + store [B,C,L].
// EPI 2: bf16 out.
// ---------------------------------------------------------------------------
template<int WM, int WN, int FM, int FN, int EPI>
__global__ __launch_bounds__(256) void gemm_bf16(
    const ushortT* __restrict__ A, const ushortT* __restrict__ B,
    void* __restrict__ Cv, const float* __restrict__ xres,
    int K, int Nreal, int ldc) {
  constexpr int BM = WM * FM * 16, BN = WN * FN * 16;
  __shared__ ushortT As[BM][72];
  __shared__ ushortT Bs[BN][72];
  int bm = blockIdx.x * BM, bn = blockIdx.y * BN;
  int tid = threadIdx.x, lane = tid & 63, w = tid >> 6;
  int wm = w / WN, wn = w % WN;
  int lm = lane & 15, lk = lane >> 4;
  const ushortT* Bb = B;
  size_t zoff = 0;
  if constexpr (EPI == 1) {
    size_t zb = blockIdx.z;
    Bb = B + zb * (size_t)LSEQ * K;
    zoff = zb * (size_t)DIMC * LSEQ;
  }
  f32x4 acc[FM][FN];
#pragma unroll
  for (int mi = 0; mi < FM; ++mi)
#pragma unroll
    for (int ni = 0; ni < FN; ++ni) acc[mi][ni] = (f32x4){0.f, 0.f, 0.f, 0.f};

  for (int k0 = 0; k0 < K; k0 += 64) {
    __syncthreads();
    for (int v = tid; v < BM * 8; v += 256) {
      int row = v >> 3, c8 = v & 7;
      *(uint4*)&As[row][c8 * 8] =
          *(const uint4*)(A + (size_t)(bm + row) * K + k0 + c8 * 8);
    }
    for (int v = tid; v < BN * 8; v += 256) {
      int row = v >> 3, c8 = v & 7;
      *(uint4*)&Bs[row][c8 * 8] =
          *(const uint4*)(Bb + (size_t)(bn + row) * K + k0 + c8 * 8);
    }
    __syncthreads();
#pragma unroll
    for (int ks = 0; ks < 2; ++ks) {
      short8 af[FM], bfr[FN];
#pragma unroll
      for (int mi = 0; mi < FM; ++mi)
        af[mi] = *(const short8*)&As[wm * FM * 16 + mi * 16 + lm][ks * 32 + lk * 8];
#pragma unroll
      for (int ni = 0; ni < FN; ++ni)
        bfr[ni] = *(const short8*)&Bs[wn * FN * 16 + ni * 16 + lm][ks * 32 + lk * 8];
#pragma unroll
      for (int mi = 0; mi < FM; ++mi)
#pragma unroll
        for (int ni = 0; ni < FN; ++ni)
          acc[mi][ni] = __builtin_amdgcn_mfma_f32_16x16x32_bf16(
              af[mi], bfr[ni], acc[mi][ni], 0, 0, 0);
    }
  }
#pragma unroll
  for (int mi = 0; mi < FM; ++mi) {
#pragma unroll
    for (int ni = 0; ni < FN; ++ni) {
      int ncol = bn + wn * FN * 16 + ni * 16 + lm;
#pragma unroll
      for (int r = 0; r < 4; ++r) {
        int m = bm + wm * FM * 16 + mi * 16 + lk * 4 + r;
        if constexpr (EPI == 0) {
          if (ncol < Nreal)
            ((float*)Cv)[(size_t)m * ldc + ncol] = acc[mi][ni][r];
        } else if constexpr (EPI == 1) {
          size_t aidx = zoff + (size_t)m * LSEQ + ncol;
          ((float*)Cv)[aidx] = xres[aidx] + acc[mi][ni][r];
        } else {
          if (ncol < Nreal)
            ((__hip_bfloat16*)Cv)[(size_t)m * ldc + ncol] =
                __float2bfloat16(acc[mi][ni][r]);
        }
      }
    }
  }
}

// ---------------------------------------------------------------------------
// K3: causal depthwise conv (k=4) + bias + SiLU  (bf16 in, bf16 out)
// ---------------------------------------------------------------------------
__global__ __launch_bounds__(256) void conv_silu_kernel(
    const __hip_bfloat16* __restrict__ xz, const float* __restrict__ conv_w,
    const float* __restrict__ conv_b, __hip_bfloat16* __restrict__ xmh) {
  int gid = blockIdx.x * 256 + threadIdx.x;
  int d = gid % DINNER;
  int tok = gid / DINNER;
  int l = tok & (LSEQ - 1);
  const float4 w = *(const float4*)(conv_w + d * 4);
  float acc = conv_b[d];
  const __hip_bfloat16* base = xz + (size_t)tok * XZW + d;
  if (l >= 3) acc = fmaf(w.x, __bfloat162float(base[-3 * XZW]), acc);
  if (l >= 2) acc = fmaf(w.y, __bfloat162float(base[-2 * XZW]), acc);
  if (l >= 1) acc = fmaf(w.z, __bfloat162float(base[-1 * XZW]), acc);
  acc = fmaf(w.w, __bfloat162float(base[0]), acc);
  float s = acc / (1.f + __expf(-acc));
  xmh[gid] = __float2bfloat16(s);
}

// ---------------------------------------------------------------------------
// Scan, d-per-lane layout: thread = (b, chunk, d); h[16]/A[16] in registers.
// dt computed in-kernel from dbc (fused dt_proj+softplus).
// ---------------------------------------------------------------------------
__device__ __forceinline__ float softplus_f(float v) {
  return v > 15.f ? v : __logf(1.f + __expf(v));
}

// K6a: chunk-local scan -> hend, pprod
__global__ __launch_bounds__(384) void scan_part1(
    const __hip_bfloat16* __restrict__ xmh, const float* __restrict__ dbc,
    const float* __restrict__ dtw, const float* __restrict__ dtb,
    const float* __restrict__ A_log,
    float* __restrict__ hend, float* __restrict__ pprod) {
  __shared__ ushortT xm_s[16 * DINNER];
  __shared__ float dbc_s[16 * 48];
  int d = threadIdx.x, c = blockIdx.x, b = blockIdx.y;
  float w12[12];
  *(float4*)&w12[0] = *(const float4*)(dtw + d * 12);
  *(float4*)&w12[4] = *(const float4*)(dtw + d * 12 + 4);
  *(float4*)&w12[8] = *(const float4*)(dtw + d * 12 + 8);
  float bias = dtb[d];
  float Ac[16];
#pragma unroll
  for (int q = 0; q < 4; ++q) {
    float4 t4 = *(const float4*)(A_log + d * 16 + q * 4);
    Ac[q * 4 + 0] = -__expf(t4.x); Ac[q * 4 + 1] = -__expf(t4.y);
    Ac[q * 4 + 2] = -__expf(t4.z); Ac[q * 4 + 3] = -__expf(t4.w);
  }
  float h[16], pa[16];
#pragma unroll
  for (int n = 0; n < 16; ++n) { h[n] = 0.f; pa[n] = 1.f; }
  size_t rowbase = (size_t)b * LSEQ + (size_t)c * LC3;
  for (int ts = 0; ts < LC3; ts += 16) {
    __syncthreads();
    {  // xm tile: 16 rows x 384 bf16, fully contiguous
      const uint4* src = (const uint4*)(xmh + (rowbase + ts) * DINNER);
      uint4* dst = (uint4*)xm_s;
      dst[d] = src[d];
      dst[d + 384] = src[d + 384];
    }
    if (d < 192) {  // dbc tile: 16 rows x 48 f32, contiguous
      ((float4*)dbc_s)[d] = ((const float4*)(dbc + (rowbase + ts) * 48))[d];
    }
    __syncthreads();
#pragma unroll
    for (int t = 0; t < 16; ++t) {
      const float* dr = &dbc_s[t * 48];
      float v = bias;
#pragma unroll
      for (int j = 0; j < 12; ++j) v = fmaf(dr[j], w12[j], v);
      float dtt = softplus_f(v);
      float xmv = __bfloat162float(((const __hip_bfloat16*)xm_s)[t * DINNER + d]);
      float dx = dtt * xmv;
      float Bv[16];
      *(float4*)&Bv[0]  = *(const float4*)&dr[12];
      *(float4*)&Bv[4]  = *(const float4*)&dr[16];
      *(float4*)&Bv[8]  = *(const float4*)&dr[20];
      *(float4*)&Bv[12] = *(const float4*)&dr[24];
#pragma unroll
      for (int n = 0; n < 16; ++n) {
        float a = __expf(dtt * Ac[n]);
        pa[n] *= a;
        h[n] = fmaf(h[n], a, dx * Bv[n]);
      }
    }
  }
  float* hp = hend  + ((size_t)(b * NCH3 + c) * DINNER + d) * 16;
  float* pp = pprod + ((size_t)(b * NCH3 + c) * DINNER + d) * 16;
#pragma unroll
  for (int q = 0; q < 4; ++q) {
    *(float4*)&hp[q * 4] = *(float4*)&h[q * 4];
    *(float4*)&pp[q * 4] = *(float4*)&pa[q * 4];
  }
}

// K6b: chunk-boundary propagation (loads independent of chain -> unroll-pipelined)
__global__ __launch_bounds__(256) void scan_part2(
    const float* __restrict__ hend, const float* __restrict__ pprod,
    float* __restrict__ hin) {
  size_t e = (size_t)blockIdx.x * 256 + threadIdx.x;   // [0, 6144)
  int b = blockIdx.y;
  float H = 0.f;
  size_t base = (size_t)b * NCH3 * DINNER * DSTATE + e;
#pragma unroll 16
  for (int c = 0; c < NCH3; ++c) {
    size_t idx = base + (size_t)c * (DINNER * DSTATE);
    hin[idx] = H;
    H = fmaf(pprod[idx], H, hend[idx]);
  }
}

// K6c: seeded chunk scan -> y (in-lane C-dot) + D-skip + SiLU gate -> ybuf bf16
__global__ __launch_bounds__(384) void scan_part3(
    const __hip_bfloat16* __restrict__ xmh, const float* __restrict__ dbc,
    const __hip_bfloat16* __restrict__ xz, const float* __restrict__ dtw,
    const float* __restrict__ dtb, const float* __restrict__ A_log,
    const float* __restrict__ Dvec, const float* __restrict__ hin,
    __hip_bfloat16* __restrict__ ybuf) {
  __shared__ ushortT xm_s[16 * DINNER];
  __shared__ ushortT z_s[16 * DINNER];
  __shared__ float dbc_s[16 * 48];
  int d = threadIdx.x, c = blockIdx.x, b = blockIdx.y;
  float w12[12];
  *(float4*)&w12[0] = *(const float4*)(dtw + d * 12);
  *(float4*)&w12[4] = *(const float4*)(dtw + d * 12 + 4);
  *(float4*)&w12[8] = *(const float4*)(dtw + d * 12 + 8);
  float bias = dtb[d];
  float Dd = Dvec[d];
  float Ac[16];
#pragma unroll
  for (int q = 0; q < 4; ++q) {
    float4 t4 = *(const float4*)(A_log + d * 16 + q * 4);
    Ac[q * 4 + 0] = -__expf(t4.x); Ac[q * 4 + 1] = -__expf(t4.y);
    Ac[q * 4 + 2] = -__expf(t4.z); Ac[q * 4 + 3] = -__expf(t4.w);
  }
  float h[16];
  const float* hp = hin + ((size_t)(b * NCH3 + c) * DINNER + d) * 16;
#pragma unroll
  for (int q = 0; q < 4; ++q) *(float4*)&h[q * 4] = *(const float4*)&hp[q * 4];
  size_t rowbase = (size_t)b * LSEQ + (size_t)c * LC3;
  for (int ts = 0; ts < LC3; ts += 16) {
    __syncthreads();
    {  // xm tile (contiguous)
      const uint4* src = (const uint4*)(xmh + (rowbase + ts) * DINNER);
      uint4* dst = (uint4*)xm_s;
      dst[d] = src[d];
      dst[d + 384] = src[d + 384];
    }
    {  // z tile: cols 384..767 of xz rows (row stride 768)
      uint4* dst = (uint4*)z_s;
      int row0 = d / 48, q0 = d % 48;
      dst[d] = *(const uint4*)(xz + (rowbase + ts + row0) * XZW + DINNER + q0 * 8);
      int v2 = d + 384;
      int row1 = v2 / 48, q1 = v2 % 48;
      dst[v2] = *(const uint4*)(xz + (rowbase + ts + row1) * XZW + DINNER + q1 * 8);
    }
    if (d < 192) {
      ((float4*)dbc_s)[d] = ((const float4*)(dbc + (rowbase + ts) * 48))[d];
    }
    __syncthreads();
#pragma unroll
    for (int t = 0; t < 16; ++t) {
      const float* dr = &dbc_s[t * 48];
      float v = bias;
#pragma unroll
      for (int j = 0; j < 12; ++j) v = fmaf(dr[j], w12[j], v);
      float dtt = softplus_f(v);
      float xmv = __bfloat162float(((const __hip_bfloat16*)xm_s)[t * DINNER + d]);
      float dx = dtt * xmv;
      float Bv[16], Cw[16];
      *(float4*)&Bv[0]  = *(const float4*)&dr[12];
      *(float4*)&Bv[4]  = *(const float4*)&dr[16];
      *(float4*)&Bv[8]  = *(const float4*)&dr[20];
      *(float4*)&Bv[12] = *(const float4*)&dr[24];
      *(float4*)&Cw[0]  = *(const float4*)&dr[28];
      *(float4*)&Cw[4]  = *(const float4*)&dr[32];
      *(float4*)&Cw[8]  = *(const float4*)&dr[36];
      *(float4*)&Cw[12] = *(const float4*)&dr[40];
      float y = 0.f;
#pragma unroll
      for (int n = 0; n < 16; ++n) {
        float a = __expf(dtt * Ac[n]);
        h[n] = fmaf(h[n], a, dx * Bv[n]);
        y = fmaf(h[n], Cw[n], y);
      }
      float yv = fmaf(xmv, Dd, y);
      float zv = __bfloat162float(((const __hip_bfloat16*)z_s)[t * DINNER + d]);
      float gt = zv / (1.f + __expf(-zv));
      ybuf[(rowbase + ts + t) * DINNER + d] = __float2bfloat16(yv * gt);
    }
  }
}

// ---------------------------------------------------------------------------
extern "C" void kernel_launch(void* const* d_in, const int* in_sizes, int n_in,
                              void* d_out, int out_size, void* d_ws, size_t ws_size,
                              hipStream_t stream) {
  const float* x        = (const float*)d_in[0];
  const float* ln_w     = (const float*)d_in[1];
  const float* ln_b     = (const float*)d_in[2];
  const float* in_proj  = (const float*)d_in[3];   // [768,192]
  const float* conv_w   = (const float*)d_in[4];   // [384,4]
  const float* conv_b   = (const float*)d_in[5];   // [384]
  const float* x_proj   = (const float*)d_in[6];   // [44,384]
  const float* dt_w     = (const float*)d_in[7];   // [384,12]
  const float* dt_b     = (const float*)d_in[8];   // [384]
  const float* A_log    = (const float*)d_in[9];   // [384,16]
  const float* Dvec     = (const float*)d_in[10];  // [384]
  const float* out_proj = (const float*)d_in[11];  // [192,384]
  float* out = (float*)d_out;

  // workspace layout (float units), total ~24.5M floats = 98 MB
  float* ws = (float*)d_ws;
  __hip_bfloat16* xzb  = (__hip_bfloat16*)ws;                    // 16384*768 bf16
  __hip_bfloat16* xmh  = (__hip_bfloat16*)(ws + 6291456);        // 16384*384 bf16
  float*          dbc  = ws + 9437184;                           // 16384*48 f32
  float*          hend = ws + 10223616;                          // NST3
  float*          pprod= hend + NST3;
  float*          hin  = pprod + NST3;
  __hip_bfloat16* ybuf = (__hip_bfloat16*)(hin + NST3);          // 16384*384 bf16
  __hip_bfloat16* xnbf = (__hip_bfloat16*)(ws + 22806528);       // 16384*192 bf16
  __hip_bfloat16* wbf  = (__hip_bfloat16*)(ws + 24379392);       // 239616 bf16

  const ushortT* win  = (const ushortT*)wbf;             // [768][192]
  const ushortT* wx   = (const ushortT*)(wbf + 147456);  // [48][384]
  const ushortT* wout = (const ushortT*)(wbf + 165888);  // [192][384]

  wcvt_kernel<<<936, 256, 0, stream>>>(in_proj, x_proj, out_proj, wbf);

  ln_kernel<<<BSZ * HSP, 256, 0, stream>>>(x, ln_w, ln_b, xnbf);

  // in_proj: [16384,192] x [768,192]^T -> xzb bf16 [16384,768]
  gemm_bf16<2, 2, 4, 2, 2><<<dim3(NTOK / 128, XZW / 64), 256, 0, stream>>>(
      (const ushortT*)xnbf, win, xzb, nullptr, DIMC, XZW, XZW);

  conv_silu_kernel<<<(NTOK * DINNER) / 256, 256, 0, stream>>>(
      xzb, conv_w, conv_b, xmh);

  // x_proj: [16384,384] x [48,384]^T -> dbc f32 [16384,48] (cols 0..43 valid)
  gemm_bf16<4, 1, 1, 3, 0><<<dim3(NTOK / 64, 1), 256, 0, stream>>>(
      (const ushortT*)xmh, wx, dbc, nullptr, DINNER, XPN, 48);

  scan_part1<<<dim3(NCH3, BSZ), 384, 0, stream>>>(
      xmh, dbc, dt_w, dt_b, A_log, hend, pprod);
  scan_part2<<<dim3(DINNER * DSTATE / 256, BSZ), 256, 0, stream>>>(
      hend, pprod, hin);
  scan_part3<<<dim3(NCH3, BSZ), 384, 0, stream>>>(
      xmh, dbc, xzb, dt_w, dt_b, A_log, Dvec, hin, ybuf);

  // out_proj: A=w_out[192][384], B=ybuf[b][4096][384] -> out[b][192][4096] + residual
  gemm_bf16<2, 2, 2, 4, 1><<<dim3(DIMC / 64, LSEQ / 128, BSZ), 256, 0, stream>>>(
      wout, (const ushortT*)ybuf, out, x, DINNER, LSEQ, LSEQ);
}

// Round 5
// 195.071 us; speedup vs baseline: 1.1359x; 1.1359x over previous
//
#include <hip/hip_runtime.h>
#include <hip/hip_bf16.h>
#include <cstdint>
#include <cmath>

#define DIMC   192
#define DSTATE 16
#define DCONV  4
#define DINNER 384
#define DTRANK 12
#define BSZ    4
#define HSP    64
#define WSP    64
#define LSEQ   4096
#define NTOK   (BSZ*LSEQ)            // 16384
#define XPN    (DTRANK + 2*DSTATE)   // 44
#define XZW    (2*DINNER)            // 768
#define LC4    16                    // scan chunk length (= one 16-token tile)
#define NCH4   (LSEQ/LC4)            // 256 chunks per batch

typedef unsigned short ushortT;
using short8 = __attribute__((ext_vector_type(8))) short;
using f32x4  = __attribute__((ext_vector_type(4))) float;

__device__ __forceinline__ float bflo(unsigned u) { return __uint_as_float(u << 16); }
__device__ __forceinline__ float bfhi(unsigned u) { return __uint_as_float(u & 0xffff0000u); }
__device__ __forceinline__ float bf2f(ushortT u) { return __uint_as_float(((unsigned)u) << 16); }
__device__ __forceinline__ unsigned pkbf(float lo, float hi) {
  __hip_bfloat16 l = __float2bfloat16(lo), h = __float2bfloat16(hi);
  return (unsigned)*(ushortT*)&l | ((unsigned)*(ushortT*)&h << 16);
}
#define UNPK8(arr, base, v4)                                        \
  arr[base + 0] = bflo(v4.x); arr[base + 1] = bfhi(v4.x);           \
  arr[base + 2] = bflo(v4.y); arr[base + 3] = bfhi(v4.y);           \
  arr[base + 4] = bflo(v4.z); arr[base + 5] = bfhi(v4.z);           \
  arr[base + 6] = bflo(v4.w); arr[base + 7] = bfhi(v4.w);

// ---------------------------------------------------------------------------
// K0: weight conversion f32 -> bf16. [in_proj 768x192][x_proj padded 48x384][out_proj 192x384]
// ---------------------------------------------------------------------------
__global__ __launch_bounds__(256) void wcvt_kernel(
    const float* __restrict__ w_in, const float* __restrict__ w_x,
    const float* __restrict__ w_out, __hip_bfloat16* __restrict__ wbf) {
  int gid = blockIdx.x * 256 + threadIdx.x;   // < 239616
  float v;
  if (gid < 147456) {
    v = w_in[gid];
  } else if (gid < 147456 + 18432) {
    int e = gid - 147456;
    int r = e / DINNER, c = e % DINNER;
    v = (r < 44) ? w_x[r * DINNER + c] : 0.f;   // rows 44..47 zero-pad
  } else {
    v = w_out[gid - 147456 - 18432];
  }
  wbf[gid] = __float2bfloat16(v);
}

// ---------------------------------------------------------------------------
// K1: [B,C,H,W] -> LayerNorm over C -> xn_bf16 [B*L, C]
// ---------------------------------------------------------------------------
__global__ __launch_bounds__(256) void ln_kernel(
    const float* __restrict__ x, const float* __restrict__ ln_w,
    const float* __restrict__ ln_b, __hip_bfloat16* __restrict__ xn) {
  __shared__ float xs[DIMC][WSP + 1];
  __shared__ float mu_s[WSP], rs_s[WSP];
  int bh = blockIdx.x;
  int b = bh >> 6, h = bh & 63;
  int tid = threadIdx.x;
  const float* xb = x + (size_t)b * DIMC * LSEQ + (size_t)h * WSP;
  for (int e = tid; e < DIMC * WSP; e += 256) {
    int c = e >> 6, w = e & 63;
    xs[c][w] = xb[(size_t)c * LSEQ + w];
  }
  __syncthreads();
  if (tid < WSP) {
    float s = 0.f, s2 = 0.f;
    for (int c = 0; c < DIMC; ++c) { float v = xs[c][tid]; s += v; s2 = fmaf(v, v, s2); }
    float mu = s * (1.f / DIMC);
    float var = s2 * (1.f / DIMC) - mu * mu;
    mu_s[tid] = mu;
    rs_s[tid] = rsqrtf(var + 1e-5f);
  }
  __syncthreads();
  __hip_bfloat16* xo = xn + (size_t)(b * LSEQ + h * WSP) * DIMC;
  for (int e = tid; e < DIMC * WSP; e += 256) {
    int w = e / DIMC, c = e % DIMC;
    xo[(size_t)w * DIMC + c] =
        __float2bfloat16((xs[c][w] - mu_s[w]) * rs_s[w] * ln_w[c] + ln_b[c]);
  }
}

// ---------------------------------------------------------------------------
// bf16 MFMA GEMM: C[M,N] = A[M,K] @ B[N,K]^T   (both row-major [dim][K] bf16)
// EPI 1: per-batch residual + f32 store [B,C,L].  EPI 2: bf16 out (guard).
// EPI 3: bf16 out with dbc column remap (n<12 -> n, else n+4), guard n<Nreal.
// ---------------------------------------------------------------------------
template<int WM, int WN, int FM, int FN, int EPI>
__global__ __launch_bounds__(256) void gemm_bf16(
    const ushortT* __restrict__ A, const ushortT* __restrict__ B,
    void* __restrict__ Cv, const float* __restrict__ xres,
    int K, int Nreal, int ldc) {
  constexpr int BM = WM * FM * 16, BN = WN * FN * 16;
  __shared__ ushortT As[BM][72];
  __shared__ ushortT Bs[BN][72];
  int bm = blockIdx.x * BM, bn = blockIdx.y * BN;
  int tid = threadIdx.x, lane = tid & 63, w = tid >> 6;
  int wm = w / WN, wn = w % WN;
  int lm = lane & 15, lk = lane >> 4;
  const ushortT* Bb = B;
  size_t zoff = 0;
  if constexpr (EPI == 1) {
    size_t zb = blockIdx.z;
    Bb = B + zb * (size_t)LSEQ * K;
    zoff = zb * (size_t)DIMC * LSEQ;
  }
  f32x4 acc[FM][FN];
#pragma unroll
  for (int mi = 0; mi < FM; ++mi)
#pragma unroll
    for (int ni = 0; ni < FN; ++ni) acc[mi][ni] = (f32x4){0.f, 0.f, 0.f, 0.f};

  for (int k0 = 0; k0 < K; k0 += 64) {
    __syncthreads();
    for (int v = tid; v < BM * 8; v += 256) {
      int row = v >> 3, c8 = v & 7;
      *(uint4*)&As[row][c8 * 8] =
          *(const uint4*)(A + (size_t)(bm + row) * K + k0 + c8 * 8);
    }
    for (int v = tid; v < BN * 8; v += 256) {
      int row = v >> 3, c8 = v & 7;
      *(uint4*)&Bs[row][c8 * 8] =
          *(const uint4*)(Bb + (size_t)(bn + row) * K + k0 + c8 * 8);
    }
    __syncthreads();
#pragma unroll
    for (int ks = 0; ks < 2; ++ks) {
      short8 af[FM], bfr[FN];
#pragma unroll
      for (int mi = 0; mi < FM; ++mi)
        af[mi] = *(const short8*)&As[wm * FM * 16 + mi * 16 + lm][ks * 32 + lk * 8];
#pragma unroll
      for (int ni = 0; ni < FN; ++ni)
        bfr[ni] = *(const short8*)&Bs[wn * FN * 16 + ni * 16 + lm][ks * 32 + lk * 8];
#pragma unroll
      for (int mi = 0; mi < FM; ++mi)
#pragma unroll
        for (int ni = 0; ni < FN; ++ni)
          acc[mi][ni] = __builtin_amdgcn_mfma_f32_16x16x32_bf16(
              af[mi], bfr[ni], acc[mi][ni], 0, 0, 0);
    }
  }
#pragma unroll
  for (int mi = 0; mi < FM; ++mi) {
#pragma unroll
    for (int ni = 0; ni < FN; ++ni) {
      int ncol = bn + wn * FN * 16 + ni * 16 + lm;
#pragma unroll
      for (int r = 0; r < 4; ++r) {
        int m = bm + wm * FM * 16 + mi * 16 + lk * 4 + r;
        if constexpr (EPI == 1) {
          size_t aidx = zoff + (size_t)m * LSEQ + ncol;
          ((float*)Cv)[aidx] = xres[aidx] + acc[mi][ni][r];
        } else if constexpr (EPI == 2) {
          if (ncol < Nreal)
            ((__hip_bfloat16*)Cv)[(size_t)m * ldc + ncol] =
                __float2bfloat16(acc[mi][ni][r]);
        } else {
          if (ncol < Nreal) {
            int nc2 = ncol < 12 ? ncol : ncol + 4;
            ((__hip_bfloat16*)Cv)[(size_t)m * ldc + nc2] =
                __float2bfloat16(acc[mi][ni][r]);
          }
        }
      }
    }
  }
}

// ---------------------------------------------------------------------------
// K3: causal depthwise conv (k=4) + bias + SiLU  (bf16 in, bf16 out)
// ---------------------------------------------------------------------------
__global__ __launch_bounds__(256) void conv_silu_kernel(
    const __hip_bfloat16* __restrict__ xz, const float* __restrict__ conv_w,
    const float* __restrict__ conv_b, __hip_bfloat16* __restrict__ xmh) {
  int gid = blockIdx.x * 256 + threadIdx.x;
  int d = gid % DINNER;
  int tok = gid / DINNER;
  int l = tok & (LSEQ - 1);
  const float4 w = *(const float4*)(conv_w + d * 4);
  float acc = conv_b[d];
  const __hip_bfloat16* base = xz + (size_t)tok * XZW + d;
  if (l >= 3) acc = fmaf(w.x, __bfloat162float(base[-3 * XZW]), acc);
  if (l >= 2) acc = fmaf(w.y, __bfloat162float(base[-2 * XZW]), acc);
  if (l >= 1) acc = fmaf(w.z, __bfloat162float(base[-1 * XZW]), acc);
  acc = fmaf(w.w, __bfloat162float(base[0]), acc);
  float s = acc / (1.f + __expf(-acc));
  xmh[gid] = __float2bfloat16(s);
}

// ---------------------------------------------------------------------------
// K5: dt = softplus(dbc[:, 0:12] @ dt_proj_w^T + dt_proj_b); write packed
// u32 (lo = dt bf16, hi = xm bf16) -> dxpk [NTOK][384]
// ---------------------------------------------------------------------------
__global__ __launch_bounds__(384) void dt_kernel(
    const ushortT* __restrict__ dbc, const __hip_bfloat16* __restrict__ xmh,
    const float* __restrict__ dtw, const float* __restrict__ dtb,
    unsigned* __restrict__ dxpk) {
  int d = threadIdx.x;
  float w12[12];
  *(float4*)&w12[0] = *(const float4*)(dtw + d * 12);
  *(float4*)&w12[4] = *(const float4*)(dtw + d * 12 + 4);
  *(float4*)&w12[8] = *(const float4*)(dtw + d * 12 + 8);
  float bias = dtb[d];
  int tok0 = blockIdx.x * 16;
  for (int tt = 0; tt < 16; ++tt) {
    int tok = tok0 + tt;
    const ushortT* row = dbc + (size_t)tok * 48;
    float v = bias;
#pragma unroll
    for (int j = 0; j < 12; ++j) v = fmaf(bf2f(row[j]), w12[j], v);
    float dt = v > 15.f ? v : __logf(1.f + __expf(v));
    float xmv = __bfloat162float(xmh[(size_t)tok * DINNER + d]);
    dxpk[(size_t)tok * DINNER + d] = pkbf(dt, xmv);
  }
}

// ---------------------------------------------------------------------------
// K6a: chunk-local scan (LC=16, one tile): h_end from 0 + decay product.
// Per t: 1 b32 (dt,xm) + 2 b128 (B bf16). exp2-direct. Output packed bf16.
// ---------------------------------------------------------------------------
__global__ __launch_bounds__(384) void scan_part1(
    const unsigned* __restrict__ dxpk, const ushortT* __restrict__ dbc,
    const float* __restrict__ A_log, unsigned* __restrict__ hpk) {
  __shared__ unsigned pk_s[16 * DINNER];
  __shared__ ushortT dbc_s[16 * 48];
  int d = threadIdx.x, c = blockIdx.x, b = blockIdx.y;
  size_t rowbase = (size_t)b * LSEQ + (size_t)c * LC4;
  {
    const uint4* src = (const uint4*)(dxpk + rowbase * DINNER);
    uint4* dst = (uint4*)pk_s;
#pragma unroll
    for (int k = 0; k < 4; ++k) dst[d + k * 384] = src[d + k * 384];
  }
  if (d < 96) {
    int row = d / 6, q = d % 6;
    ((uint4*)dbc_s)[d] = ((const uint4*)(dbc + (rowbase + row) * 48))[q];
  }
  float Ac2[16];
#pragma unroll
  for (int q = 0; q < 4; ++q) {
    float4 t4 = *(const float4*)(A_log + d * 16 + q * 4);
    Ac2[q * 4 + 0] = -__expf(t4.x) * 1.44269504f;
    Ac2[q * 4 + 1] = -__expf(t4.y) * 1.44269504f;
    Ac2[q * 4 + 2] = -__expf(t4.z) * 1.44269504f;
    Ac2[q * 4 + 3] = -__expf(t4.w) * 1.44269504f;
  }
  float h[16];
#pragma unroll
  for (int n = 0; n < 16; ++n) h[n] = 0.f;
  float sdt = 0.f;
  __syncthreads();
#pragma unroll
  for (int t = 0; t < 16; ++t) {
    unsigned w = pk_s[t * 384 + d];
    float dtt = bflo(w), xmv = bfhi(w);
    sdt += dtt;
    float dx = dtt * xmv;
    const char* bb = (const char*)dbc_s + t * 96;
    uint4 B0 = *(const uint4*)(bb + 32);
    uint4 B1 = *(const uint4*)(bb + 48);
    float Bv[16];
    UNPK8(Bv, 0, B0)
    UNPK8(Bv, 8, B1)
#pragma unroll
    for (int n = 0; n < 16; ++n) {
      float a = __builtin_amdgcn_exp2f(dtt * Ac2[n]);
      h[n] = fmaf(h[n], a, dx * Bv[n]);
    }
  }
  unsigned up[16];
#pragma unroll
  for (int n = 0; n < 16; ++n)
    up[n] = pkbf(h[n], __builtin_amdgcn_exp2f(Ac2[n] * sdt));
  uint4* hp4 = (uint4*)(hpk + (((size_t)b * NCH4 + c) * DINNER + d) * 16);
#pragma unroll
  for (int q = 0; q < 4; ++q) hp4[q] = *(uint4*)&up[q * 4];
}

// ---------------------------------------------------------------------------
// K6b: sequential chunk-boundary propagation: hin[c] = state entering chunk c
// ---------------------------------------------------------------------------
__global__ __launch_bounds__(256) void scan_part2(
    const unsigned* __restrict__ hpk, ushortT* __restrict__ hinb) {
  int e = blockIdx.x * 256 + threadIdx.x;   // [0, 6144)
  int b = blockIdx.y;
  float H = 0.f;
  size_t base = (size_t)b * NCH4 * (DINNER * DSTATE) + e;
#pragma unroll 8
  for (int c = 0; c < NCH4; ++c) {
    size_t idx = base + (size_t)c * (DINNER * DSTATE);
    unsigned w = hpk[idx];
    __hip_bfloat16 hb = __float2bfloat16(H);
    hinb[idx] = *(ushortT*)&hb;
    H = fmaf(bfhi(w), H, bflo(w));   // pa = hi, h_end = lo
  }
}

// ---------------------------------------------------------------------------
// K6c: seeded chunk scan -> y (in-lane C-dot, 4 partials) + D-skip + SiLU gate
// ---------------------------------------------------------------------------
__global__ __launch_bounds__(384) void scan_part3(
    const unsigned* __restrict__ dxpk, const ushortT* __restrict__ dbc,
    const __hip_bfloat16* __restrict__ xz, const float* __restrict__ A_log,
    const float* __restrict__ Dvec, const ushortT* __restrict__ hinb,
    __hip_bfloat16* __restrict__ ybuf) {
  __shared__ unsigned pk_s[16 * DINNER];
  __shared__ ushortT z_s[16 * DINNER];
  __shared__ ushortT dbc_s[16 * 48];
  int d = threadIdx.x, c = blockIdx.x, b = blockIdx.y;
  size_t rowbase = (size_t)b * LSEQ + (size_t)c * LC4;
  {
    const uint4* src = (const uint4*)(dxpk + rowbase * DINNER);
    uint4* dst = (uint4*)pk_s;
#pragma unroll
    for (int k = 0; k < 4; ++k) dst[d + k * 384] = src[d + k * 384];
  }
  {
    uint4* dst = (uint4*)z_s;
#pragma unroll
    for (int k = 0; k < 2; ++k) {
      int v = d + k * 384;           // [0,768)
      int row = v / 48, q = v % 48;
      dst[v] = *(const uint4*)(xz + (rowbase + row) * XZW + DINNER + q * 8);
    }
  }
  if (d < 96) {
    int row = d / 6, q = d % 6;
    ((uint4*)dbc_s)[d] = ((const uint4*)(dbc + (rowbase + row) * 48))[q];
  }
  float Ac2[16];
#pragma unroll
  for (int q = 0; q < 4; ++q) {
    float4 t4 = *(const float4*)(A_log + d * 16 + q * 4);
    Ac2[q * 4 + 0] = -__expf(t4.x) * 1.44269504f;
    Ac2[q * 4 + 1] = -__expf(t4.y) * 1.44269504f;
    Ac2[q * 4 + 2] = -__expf(t4.z) * 1.44269504f;
    Ac2[q * 4 + 3] = -__expf(t4.w) * 1.44269504f;
  }
  float h[16];
  {
    const uint4* hp = (const uint4*)(hinb + (((size_t)b * NCH4 + c) * DINNER + d) * 16);
    uint4 h0 = hp[0], h1 = hp[1];
    UNPK8(h, 0, h0)
    UNPK8(h, 8, h1)
  }
  float Dd = Dvec[d];
  __syncthreads();
#pragma unroll
  for (int t = 0; t < 16; ++t) {
    unsigned w = pk_s[t * 384 + d];
    float dtt = bflo(w), xmv = bfhi(w);
    float dx = dtt * xmv;
    const char* bb = (const char*)dbc_s + t * 96;
    uint4 B0 = *(const uint4*)(bb + 32);
    uint4 B1 = *(const uint4*)(bb + 48);
    uint4 C0 = *(const uint4*)(bb + 64);
    uint4 C1 = *(const uint4*)(bb + 80);
    float Bv[16], Cw[16];
    UNPK8(Bv, 0, B0)
    UNPK8(Bv, 8, B1)
    UNPK8(Cw, 0, C0)
    UNPK8(Cw, 8, C1)
    float y0 = 0.f, y1 = 0.f, y2 = 0.f, y3 = 0.f;
#pragma unroll
    for (int n = 0; n < 16; n += 4) {
      float a0 = __builtin_amdgcn_exp2f(dtt * Ac2[n + 0]);
      float a1 = __builtin_amdgcn_exp2f(dtt * Ac2[n + 1]);
      float a2 = __builtin_amdgcn_exp2f(dtt * Ac2[n + 2]);
      float a3 = __builtin_amdgcn_exp2f(dtt * Ac2[n + 3]);
      h[n + 0] = fmaf(h[n + 0], a0, dx * Bv[n + 0]);
      h[n + 1] = fmaf(h[n + 1], a1, dx * Bv[n + 1]);
      h[n + 2] = fmaf(h[n + 2], a2, dx * Bv[n + 2]);
      h[n + 3] = fmaf(h[n + 3], a3, dx * Bv[n + 3]);
      y0 = fmaf(h[n + 0], Cw[n + 0], y0);
      y1 = fmaf(h[n + 1], Cw[n + 1], y1);
      y2 = fmaf(h[n + 2], Cw[n + 2], y2);
      y3 = fmaf(h[n + 3], Cw[n + 3], y3);
    }
    float yv = fmaf(xmv, Dd, (y0 + y1) + (y2 + y3));
    float zv = bf2f(z_s[t * 384 + d]);
    float gt = zv / (1.f + __expf(-zv));
    ybuf[(rowbase + t) * DINNER + d] = __float2bfloat16(yv * gt);
  }
}

// ---------------------------------------------------------------------------
extern "C" void kernel_launch(void* const* d_in, const int* in_sizes, int n_in,
                              void* d_out, int out_size, void* d_ws, size_t ws_size,
                              hipStream_t stream) {
  const float* x        = (const float*)d_in[0];
  const float* ln_w     = (const float*)d_in[1];
  const float* ln_b     = (const float*)d_in[2];
  const float* in_proj  = (const float*)d_in[3];   // [768,192]
  const float* conv_w   = (const float*)d_in[4];   // [384,4]
  const float* conv_b   = (const float*)d_in[5];   // [384]
  const float* x_proj   = (const float*)d_in[6];   // [44,384]
  const float* dt_w     = (const float*)d_in[7];   // [384,12]
  const float* dt_b     = (const float*)d_in[8];   // [384]
  const float* A_log    = (const float*)d_in[9];   // [384,16]
  const float* Dvec     = (const float*)d_in[10];  // [384]
  const float* out_proj = (const float*)d_in[11];  // [192,384]
  float* out = (float*)d_out;

  // workspace layout (float units), total ~30.4M floats = 121.6 MB
  float* ws = (float*)d_ws;
  __hip_bfloat16* xzb  = (__hip_bfloat16*)ws;                    // [16384][768] bf16
  __hip_bfloat16* xmh  = (__hip_bfloat16*)(ws + 6291456);        // [16384][384] bf16
  ushortT*        dbcb = (ushortT*)(ws + 9437184);               // [16384][48] bf16 (remapped cols)
  unsigned*       dxpk = (unsigned*)(ws + 9830400);              // [16384][384] u32 (dt,xm)
  unsigned*       hpk  = (unsigned*)(ws + 16121856);             // [4][256][384][16] u32 (h,pa)
  ushortT*        hinb = (ushortT*)(ws + 22413312);              // same shape bf16
  __hip_bfloat16* ybuf = (__hip_bfloat16*)(ws + 25559040);       // [16384][384] bf16
  __hip_bfloat16* xnbf = (__hip_bfloat16*)(ws + 28704768);       // [16384][192] bf16
  __hip_bfloat16* wbf  = (__hip_bfloat16*)(ws + 30277632);       // 239616 bf16

  const ushortT* win  = (const ushortT*)wbf;             // [768][192]
  const ushortT* wx   = (const ushortT*)(wbf + 147456);  // [48][384]
  const ushortT* wout = (const ushortT*)(wbf + 165888);  // [192][384]

  wcvt_kernel<<<936, 256, 0, stream>>>(in_proj, x_proj, out_proj, wbf);

  ln_kernel<<<BSZ * HSP, 256, 0, stream>>>(x, ln_w, ln_b, xnbf);

  // in_proj: [16384,192] x [768,192]^T -> xzb bf16 [16384,768]
  gemm_bf16<2, 2, 4, 2, 2><<<dim3(NTOK / 128, XZW / 64), 256, 0, stream>>>(
      (const ushortT*)xnbf, win, xzb, nullptr, DIMC, XZW, XZW);

  conv_silu_kernel<<<(NTOK * DINNER) / 256, 256, 0, stream>>>(
      xzb, conv_w, conv_b, xmh);

  // x_proj: [16384,384] x [48,384]^T -> dbcb bf16 [16384,48], cols remapped
  gemm_bf16<4, 1, 1, 3, 3><<<dim3(NTOK / 64, 1), 256, 0, stream>>>(
      (const ushortT*)xmh, wx, dbcb, nullptr, DINNER, XPN, 48);

  dt_kernel<<<NTOK / 16, 384, 0, stream>>>(dbcb, xmh, dt_w, dt_b, dxpk);

  scan_part1<<<dim3(NCH4, BSZ), 384, 0, stream>>>(dxpk, dbcb, A_log, hpk);
  scan_part2<<<dim3(DINNER * DSTATE / 256, BSZ), 256, 0, stream>>>(hpk, hinb);
  scan_part3<<<dim3(NCH4, BSZ), 384, 0, stream>>>(
      dxpk, dbcb, xzb, A_log, Dvec, hinb, ybuf);

  // out_proj: A=w_out[192][384], B=ybuf[b][4096][384] -> out[b][192][4096] + residual
  gemm_bf16<2, 2, 2, 4, 1><<<dim3(DIMC / 64, LSEQ / 128, BSZ), 256, 0, stream>>>(
      wout, (const ushortT*)ybuf, out, x, DINNER, LSEQ, LSEQ);
}

// Round 6
// 177.086 us; speedup vs baseline: 1.2513x; 1.1016x over previous
//
#include <hip/hip_runtime.h>
#include <hip/hip_bf16.h>
#include <cstdint>
#include <cmath>

#define DIMC   192
#define DSTATE 16
#define DCONV  4
#define DINNER 384
#define DTRANK 12
#define BSZ    4
#define HSP    64
#define WSP    64
#define LSEQ   4096
#define NTOK   (BSZ*LSEQ)            // 16384
#define XPN    (DTRANK + 2*DSTATE)   // 44
#define XZW    (2*DINNER)            // 768
#define LC4    16                    // scan chunk length (= one 16-token tile)
#define NCH4   (LSEQ/LC4)            // 256 chunks per batch

typedef unsigned short ushortT;
using short8 = __attribute__((ext_vector_type(8))) short;
using f32x4  = __attribute__((ext_vector_type(4))) float;

__device__ __forceinline__ float bflo(unsigned u) { return __uint_as_float(u << 16); }
__device__ __forceinline__ float bfhi(unsigned u) { return __uint_as_float(u & 0xffff0000u); }
__device__ __forceinline__ float bf2f(ushortT u) { return __uint_as_float(((unsigned)u) << 16); }
__device__ __forceinline__ unsigned pkbf(float lo, float hi) {
  __hip_bfloat16 l = __float2bfloat16(lo), h = __float2bfloat16(hi);
  return (unsigned)*(ushortT*)&l | ((unsigned)*(ushortT*)&h << 16);
}
#define UNPK8(arr, base, v4)                                        \
  arr[base + 0] = bflo(v4.x); arr[base + 1] = bfhi(v4.x);           \
  arr[base + 2] = bflo(v4.y); arr[base + 3] = bfhi(v4.y);           \
  arr[base + 4] = bflo(v4.z); arr[base + 5] = bfhi(v4.z);           \
  arr[base + 6] = bflo(v4.w); arr[base + 7] = bfhi(v4.w);

// ---------------------------------------------------------------------------
// K0: weight conversion f32 -> bf16. [in_proj 768x192][x_proj padded 48x384][out_proj 192x384]
// ---------------------------------------------------------------------------
__global__ __launch_bounds__(256) void wcvt_kernel(
    const float* __restrict__ w_in, const float* __restrict__ w_x,
    const float* __restrict__ w_out, __hip_bfloat16* __restrict__ wbf) {
  int gid = blockIdx.x * 256 + threadIdx.x;   // < 239616
  float v;
  if (gid < 147456) {
    v = w_in[gid];
  } else if (gid < 147456 + 18432) {
    int e = gid - 147456;
    int r = e / DINNER, c = e % DINNER;
    v = (r < 44) ? w_x[r * DINNER + c] : 0.f;   // rows 44..47 zero-pad
  } else {
    v = w_out[gid - 147456 - 18432];
  }
  wbf[gid] = __float2bfloat16(v);
}

// ---------------------------------------------------------------------------
// K1: [B,C,H,W] -> LayerNorm over C -> xn_bf16 [B*L, C]
// 512 threads; stats via 8-lanes-per-token shfl reduce.
// ---------------------------------------------------------------------------
__global__ __launch_bounds__(512) void ln_kernel(
    const float* __restrict__ x, const float* __restrict__ ln_w,
    const float* __restrict__ ln_b, __hip_bfloat16* __restrict__ xn) {
  __shared__ float xs[DIMC][WSP + 1];
  __shared__ float mu_s[WSP], rs_s[WSP];
  int bh = blockIdx.x;
  int b = bh >> 6, h = bh & 63;
  int tid = threadIdx.x;
  const float* xb = x + (size_t)b * DIMC * LSEQ + (size_t)h * WSP;
  for (int e = tid; e < DIMC * WSP; e += 512) {
    int c = e >> 6, w = e & 63;
    xs[c][w] = xb[(size_t)c * LSEQ + w];
  }
  __syncthreads();
  {
    int w = tid >> 3, p = tid & 7;     // token w, part p: 24 channels each
    float s = 0.f, s2 = 0.f;
#pragma unroll
    for (int i = 0; i < 24; ++i) {
      float v = xs[p * 24 + i][w];
      s += v; s2 = fmaf(v, v, s2);
    }
    s  += __shfl_xor(s, 1);  s2 += __shfl_xor(s2, 1);
    s  += __shfl_xor(s, 2);  s2 += __shfl_xor(s2, 2);
    s  += __shfl_xor(s, 4);  s2 += __shfl_xor(s2, 4);
    if (p == 0) {
      float mu = s * (1.f / DIMC);
      float var = s2 * (1.f / DIMC) - mu * mu;
      mu_s[w] = mu;
      rs_s[w] = rsqrtf(var + 1e-5f);
    }
  }
  __syncthreads();
  __hip_bfloat16* xo = xn + (size_t)(b * LSEQ + h * WSP) * DIMC;
  for (int e = tid; e < DIMC * WSP; e += 512) {
    int w = e / DIMC, c = e % DIMC;
    xo[(size_t)w * DIMC + c] =
        __float2bfloat16((xs[c][w] - mu_s[w]) * rs_s[w] * ln_w[c] + ln_b[c]);
  }
}

// ---------------------------------------------------------------------------
// bf16 MFMA GEMM: C[M,N] = A[M,K] @ B[N,K]^T   (both row-major [dim][K] bf16)
// EPI 1: per-batch residual + f32 store [B,C,L].  EPI 2: bf16 out (guard).
// EPI 3: bf16 out with dbc column remap (n<12 -> n, else n+4), guard n<Nreal.
// ---------------------------------------------------------------------------
template<int WM, int WN, int FM, int FN, int EPI>
__global__ __launch_bounds__(256) void gemm_bf16(
    const ushortT* __restrict__ A, const ushortT* __restrict__ B,
    void* __restrict__ Cv, const float* __restrict__ xres,
    int K, int Nreal, int ldc) {
  constexpr int BM = WM * FM * 16, BN = WN * FN * 16;
  __shared__ ushortT As[BM][72];
  __shared__ ushortT Bs[BN][72];
  int bm = blockIdx.x * BM, bn = blockIdx.y * BN;
  int tid = threadIdx.x, lane = tid & 63, w = tid >> 6;
  int wm = w / WN, wn = w % WN;
  int lm = lane & 15, lk = lane >> 4;
  const ushortT* Bb = B;
  size_t zoff = 0;
  if constexpr (EPI == 1) {
    size_t zb = blockIdx.z;
    Bb = B + zb * (size_t)LSEQ * K;
    zoff = zb * (size_t)DIMC * LSEQ;
  }
  f32x4 acc[FM][FN];
#pragma unroll
  for (int mi = 0; mi < FM; ++mi)
#pragma unroll
    for (int ni = 0; ni < FN; ++ni) acc[mi][ni] = (f32x4){0.f, 0.f, 0.f, 0.f};

  for (int k0 = 0; k0 < K; k0 += 64) {
    __syncthreads();
    for (int v = tid; v < BM * 8; v += 256) {
      int row = v >> 3, c8 = v & 7;
      *(uint4*)&As[row][c8 * 8] =
          *(const uint4*)(A + (size_t)(bm + row) * K + k0 + c8 * 8);
    }
    for (int v = tid; v < BN * 8; v += 256) {
      int row = v >> 3, c8 = v & 7;
      *(uint4*)&Bs[row][c8 * 8] =
          *(const uint4*)(Bb + (size_t)(bn + row) * K + k0 + c8 * 8);
    }
    __syncthreads();
#pragma unroll
    for (int ks = 0; ks < 2; ++ks) {
      short8 af[FM], bfr[FN];
#pragma unroll
      for (int mi = 0; mi < FM; ++mi)
        af[mi] = *(const short8*)&As[wm * FM * 16 + mi * 16 + lm][ks * 32 + lk * 8];
#pragma unroll
      for (int ni = 0; ni < FN; ++ni)
        bfr[ni] = *(const short8*)&Bs[wn * FN * 16 + ni * 16 + lm][ks * 32 + lk * 8];
#pragma unroll
      for (int mi = 0; mi < FM; ++mi)
#pragma unroll
        for (int ni = 0; ni < FN; ++ni)
          acc[mi][ni] = __builtin_amdgcn_mfma_f32_16x16x32_bf16(
              af[mi], bfr[ni], acc[mi][ni], 0, 0, 0);
    }
  }
#pragma unroll
  for (int mi = 0; mi < FM; ++mi) {
#pragma unroll
    for (int ni = 0; ni < FN; ++ni) {
      int ncol = bn + wn * FN * 16 + ni * 16 + lm;
#pragma unroll
      for (int r = 0; r < 4; ++r) {
        int m = bm + wm * FM * 16 + mi * 16 + lk * 4 + r;
        if constexpr (EPI == 1) {
          size_t aidx = zoff + (size_t)m * LSEQ + ncol;
          ((float*)Cv)[aidx] = xres[aidx] + acc[mi][ni][r];
        } else if constexpr (EPI == 2) {
          if (ncol < Nreal)
            ((__hip_bfloat16*)Cv)[(size_t)m * ldc + ncol] =
                __float2bfloat16(acc[mi][ni][r]);
        } else {
          if (ncol < Nreal) {
            int nc2 = ncol < 12 ? ncol : ncol + 4;
            ((__hip_bfloat16*)Cv)[(size_t)m * ldc + nc2] =
                __float2bfloat16(acc[mi][ni][r]);
          }
        }
      }
    }
  }
}

// ---------------------------------------------------------------------------
// K3: causal depthwise conv (k=4) + bias + SiLU  (bf16 in, bf16 out)
// ---------------------------------------------------------------------------
__global__ __launch_bounds__(256) void conv_silu_kernel(
    const __hip_bfloat16* __restrict__ xz, const float* __restrict__ conv_w,
    const float* __restrict__ conv_b, __hip_bfloat16* __restrict__ xmh) {
  int gid = blockIdx.x * 256 + threadIdx.x;
  int d = gid % DINNER;
  int tok = gid / DINNER;
  int l = tok & (LSEQ - 1);
  const float4 w = *(const float4*)(conv_w + d * 4);
  float acc = conv_b[d];
  const __hip_bfloat16* base = xz + (size_t)tok * XZW + d;
  if (l >= 3) acc = fmaf(w.x, __bfloat162float(base[-3 * XZW]), acc);
  if (l >= 2) acc = fmaf(w.y, __bfloat162float(base[-2 * XZW]), acc);
  if (l >= 1) acc = fmaf(w.z, __bfloat162float(base[-1 * XZW]), acc);
  acc = fmaf(w.w, __bfloat162float(base[0]), acc);
  float s = acc / (1.f + __expf(-acc));
  xmh[gid] = __float2bfloat16(s);
}

// ---------------------------------------------------------------------------
// K5: dt = softplus(dbc[:, 0:12] @ dt_proj_w^T + dt_proj_b); write packed
// u32 (lo = dt bf16, hi = xm bf16) -> dxpk [NTOK][384]
// ---------------------------------------------------------------------------
__global__ __launch_bounds__(384) void dt_kernel(
    const ushortT* __restrict__ dbc, const __hip_bfloat16* __restrict__ xmh,
    const float* __restrict__ dtw, const float* __restrict__ dtb,
    unsigned* __restrict__ dxpk) {
  int d = threadIdx.x;
  float w12[12];
  *(float4*)&w12[0] = *(const float4*)(dtw + d * 12);
  *(float4*)&w12[4] = *(const float4*)(dtw + d * 12 + 4);
  *(float4*)&w12[8] = *(const float4*)(dtw + d * 12 + 8);
  float bias = dtb[d];
  int tok0 = blockIdx.x * 16;
  for (int tt = 0; tt < 16; ++tt) {
    int tok = tok0 + tt;
    const ushortT* row = dbc + (size_t)tok * 48;
    float v = bias;
#pragma unroll
    for (int j = 0; j < 12; ++j) v = fmaf(bf2f(row[j]), w12[j], v);
    float dt = v > 15.f ? v : __logf(1.f + __expf(v));
    float xmv = __bfloat162float(xmh[(size_t)tok * DINNER + d]);
    dxpk[(size_t)tok * DINNER + d] = pkbf(dt, xmv);
  }
}

// ---------------------------------------------------------------------------
// K6a: chunk-local scan (LC=16): h_end from 0 + decay product.
// Direct coalesced global loads of (dt,xm); only dbc tile in LDS (broadcast).
// ---------------------------------------------------------------------------
__global__ __launch_bounds__(384) void scan_part1(
    const unsigned* __restrict__ dxpk, const ushortT* __restrict__ dbc,
    const float* __restrict__ A_log, unsigned* __restrict__ hpk) {
  __shared__ ushortT dbc_s[16 * 48];
  int d = threadIdx.x, c = blockIdx.x, b = blockIdx.y;
  size_t rowbase = (size_t)b * LSEQ + (size_t)c * LC4;
  if (d < 96) {
    int row = d / 6, q = d % 6;
    ((uint4*)dbc_s)[d] = ((const uint4*)(dbc + (rowbase + row) * 48))[q];
  }
  float Ac2[16];
#pragma unroll
  for (int q = 0; q < 4; ++q) {
    float4 t4 = *(const float4*)(A_log + d * 16 + q * 4);
    Ac2[q * 4 + 0] = -__expf(t4.x) * 1.44269504f;
    Ac2[q * 4 + 1] = -__expf(t4.y) * 1.44269504f;
    Ac2[q * 4 + 2] = -__expf(t4.z) * 1.44269504f;
    Ac2[q * 4 + 3] = -__expf(t4.w) * 1.44269504f;
  }
  float h[16];
#pragma unroll
  for (int n = 0; n < 16; ++n) h[n] = 0.f;
  float sdt = 0.f;
  const unsigned* pkp = dxpk + rowbase * DINNER + d;
  __syncthreads();
#pragma unroll
  for (int t0 = 0; t0 < 16; t0 += 4) {
    unsigned pk[4];
#pragma unroll
    for (int j = 0; j < 4; ++j) pk[j] = pkp[(t0 + j) * DINNER];
#pragma unroll
    for (int j = 0; j < 4; ++j) {
      int t = t0 + j;
      float dtt = bflo(pk[j]), xmv = bfhi(pk[j]);
      sdt += dtt;
      float dx = dtt * xmv;
      const char* bb = (const char*)dbc_s + t * 96;
      uint4 B0 = *(const uint4*)(bb + 32);
      uint4 B1 = *(const uint4*)(bb + 48);
      float Bv[16];
      UNPK8(Bv, 0, B0)
      UNPK8(Bv, 8, B1)
#pragma unroll
      for (int n = 0; n < 16; ++n) {
        float a = __builtin_amdgcn_exp2f(dtt * Ac2[n]);
        h[n] = fmaf(h[n], a, dx * Bv[n]);
      }
    }
  }
  unsigned up[16];
#pragma unroll
  for (int n = 0; n < 16; ++n)
    up[n] = pkbf(h[n], __builtin_amdgcn_exp2f(Ac2[n] * sdt));
  uint4* hp4 = (uint4*)(hpk + (((size_t)b * NCH4 + c) * DINNER + d) * 16);
#pragma unroll
  for (int q = 0; q < 4; ++q) hp4[q] = *(uint4*)&up[q * 4];
}

// ---------------------------------------------------------------------------
// K6b: sequential chunk-boundary propagation: hin[c] = state entering chunk c
// ---------------------------------------------------------------------------
__global__ __launch_bounds__(256) void scan_part2(
    const unsigned* __restrict__ hpk, ushortT* __restrict__ hinb) {
  int e = blockIdx.x * 256 + threadIdx.x;   // [0, 6144)
  int b = blockIdx.y;
  float H = 0.f;
  size_t base = (size_t)b * NCH4 * (DINNER * DSTATE) + e;
#pragma unroll 16
  for (int c = 0; c < NCH4; ++c) {
    size_t idx = base + (size_t)c * (DINNER * DSTATE);
    unsigned w = hpk[idx];
    __hip_bfloat16 hb = __float2bfloat16(H);
    hinb[idx] = *(ushortT*)&hb;
    H = fmaf(bfhi(w), H, bflo(w));   // pa = hi, h_end = lo
  }
}

// ---------------------------------------------------------------------------
// K6c: seeded chunk scan -> y (in-lane C-dot) + D-skip + SiLU gate -> ybuf
// Direct coalesced global loads of (dt,xm) and z; only dbc tile in LDS.
// ---------------------------------------------------------------------------
__global__ __launch_bounds__(384) void scan_part3(
    const unsigned* __restrict__ dxpk, const ushortT* __restrict__ dbc,
    const __hip_bfloat16* __restrict__ xz, const float* __restrict__ A_log,
    const float* __restrict__ Dvec, const ushortT* __restrict__ hinb,
    __hip_bfloat16* __restrict__ ybuf) {
  __shared__ ushortT dbc_s[16 * 48];
  int d = threadIdx.x, c = blockIdx.x, b = blockIdx.y;
  size_t rowbase = (size_t)b * LSEQ + (size_t)c * LC4;
  if (d < 96) {
    int row = d / 6, q = d % 6;
    ((uint4*)dbc_s)[d] = ((const uint4*)(dbc + (rowbase + row) * 48))[q];
  }
  float Ac2[16];
#pragma unroll
  for (int q = 0; q < 4; ++q) {
    float4 t4 = *(const float4*)(A_log + d * 16 + q * 4);
    Ac2[q * 4 + 0] = -__expf(t4.x) * 1.44269504f;
    Ac2[q * 4 + 1] = -__expf(t4.y) * 1.44269504f;
    Ac2[q * 4 + 2] = -__expf(t4.z) * 1.44269504f;
    Ac2[q * 4 + 3] = -__expf(t4.w) * 1.44269504f;
  }
  float h[16];
  {
    const uint4* hp = (const uint4*)(hinb + (((size_t)b * NCH4 + c) * DINNER + d) * 16);
    uint4 h0 = hp[0], h1 = hp[1];
    UNPK8(h, 0, h0)
    UNPK8(h, 8, h1)
  }
  float Dd = Dvec[d];
  const unsigned* pkp = dxpk + rowbase * DINNER + d;
  const ushortT* zp = (const ushortT*)xz + rowbase * XZW + DINNER + d;
  __hip_bfloat16* yp = ybuf + rowbase * DINNER + d;
  __syncthreads();
#pragma unroll
  for (int t0 = 0; t0 < 16; t0 += 4) {
    unsigned pk[4];
    ushortT zv4[4];
#pragma unroll
    for (int j = 0; j < 4; ++j) {
      pk[j] = pkp[(t0 + j) * DINNER];
      zv4[j] = zp[(t0 + j) * XZW];
    }
#pragma unroll
    for (int j = 0; j < 4; ++j) {
      int t = t0 + j;
      float dtt = bflo(pk[j]), xmv = bfhi(pk[j]);
      float dx = dtt * xmv;
      const char* bb = (const char*)dbc_s + t * 96;
      uint4 B0 = *(const uint4*)(bb + 32);
      uint4 B1 = *(const uint4*)(bb + 48);
      uint4 C0 = *(const uint4*)(bb + 64);
      uint4 C1 = *(const uint4*)(bb + 80);
      float Bv[16], Cw[16];
      UNPK8(Bv, 0, B0)
      UNPK8(Bv, 8, B1)
      UNPK8(Cw, 0, C0)
      UNPK8(Cw, 8, C1)
      float y0 = 0.f, y1 = 0.f, y2 = 0.f, y3 = 0.f;
#pragma unroll
      for (int n = 0; n < 16; n += 4) {
        float a0 = __builtin_amdgcn_exp2f(dtt * Ac2[n + 0]);
        float a1 = __builtin_amdgcn_exp2f(dtt * Ac2[n + 1]);
        float a2 = __builtin_amdgcn_exp2f(dtt * Ac2[n + 2]);
        float a3 = __builtin_amdgcn_exp2f(dtt * Ac2[n + 3]);
        h[n + 0] = fmaf(h[n + 0], a0, dx * Bv[n + 0]);
        h[n + 1] = fmaf(h[n + 1], a1, dx * Bv[n + 1]);
        h[n + 2] = fmaf(h[n + 2], a2, dx * Bv[n + 2]);
        h[n + 3] = fmaf(h[n + 3], a3, dx * Bv[n + 3]);
        y0 = fmaf(h[n + 0], Cw[n + 0], y0);
        y1 = fmaf(h[n + 1], Cw[n + 1], y1);
        y2 = fmaf(h[n + 2], Cw[n + 2], y2);
        y3 = fmaf(h[n + 3], Cw[n + 3], y3);
      }
      float yv = fmaf(xmv, Dd, (y0 + y1) + (y2 + y3));
      float zv = bf2f(zv4[j]);
      float gt = zv * __builtin_amdgcn_rcpf(
          1.f + __builtin_amdgcn_exp2f(zv * -1.44269504f));
      yp[(size_t)t * DINNER] = __float2bfloat16(yv * gt);
    }
  }
}

// ---------------------------------------------------------------------------
extern "C" void kernel_launch(void* const* d_in, const int* in_sizes, int n_in,
                              void* d_out, int out_size, void* d_ws, size_t ws_size,
                              hipStream_t stream) {
  const float* x        = (const float*)d_in[0];
  const float* ln_w     = (const float*)d_in[1];
  const float* ln_b     = (const float*)d_in[2];
  const float* in_proj  = (const float*)d_in[3];   // [768,192]
  const float* conv_w   = (const float*)d_in[4];   // [384,4]
  const float* conv_b   = (const float*)d_in[5];   // [384]
  const float* x_proj   = (const float*)d_in[6];   // [44,384]
  const float* dt_w     = (const float*)d_in[7];   // [384,12]
  const float* dt_b     = (const float*)d_in[8];   // [384]
  const float* A_log    = (const float*)d_in[9];   // [384,16]
  const float* Dvec     = (const float*)d_in[10];  // [384]
  const float* out_proj = (const float*)d_in[11];  // [192,384]
  float* out = (float*)d_out;

  // workspace layout (float units), total ~30.4M floats = 121.6 MB
  float* ws = (float*)d_ws;
  __hip_bfloat16* xzb  = (__hip_bfloat16*)ws;                    // [16384][768] bf16
  __hip_bfloat16* xmh  = (__hip_bfloat16*)(ws + 6291456);        // [16384][384] bf16
  ushortT*        dbcb = (ushortT*)(ws + 9437184);               // [16384][48] bf16 (remapped cols)
  unsigned*       dxpk = (unsigned*)(ws + 9830400);              // [16384][384] u32 (dt,xm)
  unsigned*       hpk  = (unsigned*)(ws + 16121856);             // [4][256][384][16] u32 (h,pa)
  ushortT*        hinb = (ushortT*)(ws + 22413312);              // same shape bf16
  __hip_bfloat16* ybuf = (__hip_bfloat16*)(ws + 25559040);       // [16384][384] bf16
  __hip_bfloat16* xnbf = (__hip_bfloat16*)(ws + 28704768);       // [16384][192] bf16
  __hip_bfloat16* wbf  = (__hip_bfloat16*)(ws + 30277632);       // 239616 bf16

  const ushortT* win  = (const ushortT*)wbf;             // [768][192]
  const ushortT* wx   = (const ushortT*)(wbf + 147456);  // [48][384]
  const ushortT* wout = (const ushortT*)(wbf + 165888);  // [192][384]

  wcvt_kernel<<<936, 256, 0, stream>>>(in_proj, x_proj, out_proj, wbf);

  ln_kernel<<<BSZ * HSP, 512, 0, stream>>>(x, ln_w, ln_b, xnbf);

  // in_proj: [16384,192] x [768,192]^T -> xzb bf16 [16384,768]
  gemm_bf16<2, 2, 4, 2, 2><<<dim3(NTOK / 128, XZW / 64), 256, 0, stream>>>(
      (const ushortT*)xnbf, win, xzb, nullptr, DIMC, XZW, XZW);

  conv_silu_kernel<<<(NTOK * DINNER) / 256, 256, 0, stream>>>(
      xzb, conv_w, conv_b, xmh);

  // x_proj: [16384,384] x [48,384]^T -> dbcb bf16 [16384,48], cols remapped
  gemm_bf16<4, 1, 1, 3, 3><<<dim3(NTOK / 64, 1), 256, 0, stream>>>(
      (const ushortT*)xmh, wx, dbcb, nullptr, DINNER, XPN, 48);

  dt_kernel<<<NTOK / 16, 384, 0, stream>>>(dbcb, xmh, dt_w, dt_b, dxpk);

  scan_part1<<<dim3(NCH4, BSZ), 384, 0, stream>>>(dxpk, dbcb, A_log, hpk);
  scan_part2<<<dim3(DINNER * DSTATE / 256, BSZ), 256, 0, stream>>>(hpk, hinb);
  scan_part3<<<dim3(NCH4, BSZ), 384, 0, stream>>>(
      dxpk, dbcb, xzb, A_log, Dvec, hinb, ybuf);

  // out_proj: A=w_out[192][384], B=ybuf[b][4096][384] -> out[b][192][4096] + residual
  gemm_bf16<2, 2, 2, 4, 1><<<dim3(DIMC / 64, LSEQ / 128, BSZ), 256, 0, stream>>>(
      wout, (const ushortT*)ybuf, out, x, DINNER, LSEQ, LSEQ);
}

// Round 7
// 174.720 us; speedup vs baseline: 1.2682x; 1.0135x over previous
//
#include <hip/hip_runtime.h>
#include <hip/hip_bf16.h>
#include <cstdint>
#include <cmath>

#define DIMC   192
#define DSTATE 16
#define DCONV  4
#define DINNER 384
#define DTRANK 12
#define BSZ    4
#define HSP    64
#define WSP    64
#define LSEQ   4096
#define NTOK   (BSZ*LSEQ)            // 16384
#define XPN    (DTRANK + 2*DSTATE)   // 44
#define XZW    (2*DINNER)            // 768
#define LC4    16                    // scan chunk length
#define NCH4   (LSEQ/LC4)            // 256 chunks per batch
#define NXP    448                   // padded fused x_proj+dt output width

typedef unsigned short ushortT;
using short8 = __attribute__((ext_vector_type(8))) short;
using f32x4  = __attribute__((ext_vector_type(4))) float;

__device__ __forceinline__ float bflo(unsigned u) { return __uint_as_float(u << 16); }
__device__ __forceinline__ float bfhi(unsigned u) { return __uint_as_float(u & 0xffff0000u); }
__device__ __forceinline__ float bf2f(ushortT u) { return __uint_as_float(((unsigned)u) << 16); }
__device__ __forceinline__ unsigned pkbf(float lo, float hi) {
  __hip_bfloat16 l = __float2bfloat16(lo), h = __float2bfloat16(hi);
  return (unsigned)*(ushortT*)&l | ((unsigned)*(ushortT*)&h << 16);
}
#define UNPK8(arr, base, v4)                                        \
  arr[base + 0] = bflo(v4.x); arr[base + 1] = bfhi(v4.x);           \
  arr[base + 2] = bflo(v4.y); arr[base + 3] = bfhi(v4.y);           \
  arr[base + 4] = bflo(v4.z); arr[base + 5] = bfhi(v4.z);           \
  arr[base + 6] = bflo(v4.w); arr[base + 7] = bfhi(v4.w);

// ---------------------------------------------------------------------------
// K0a: f32 -> bf16 weight conversion: [in_proj 768x192][out_proj 192x384]
// ---------------------------------------------------------------------------
__global__ __launch_bounds__(256) void wcvt_kernel(
    const float* __restrict__ w_in, const float* __restrict__ w_out,
    __hip_bfloat16* __restrict__ wbf) {
  int gid = blockIdx.x * 256 + threadIdx.x;   // < 221184
  float v = gid < 147456 ? w_in[gid] : w_out[gid - 147456];
  wbf[gid] = __float2bfloat16(v);
}

// ---------------------------------------------------------------------------
// K0b: combined weight [448][384]:
//   rows 0..383   : Wcomb[d][k] = sum_j dtw[d][j] * x_proj_w[j][k]
//   rows 384..415 : x_proj_w[12 + (row-384)][k]   (B then C rows)
//   rows 416..447 : zero pad
// ---------------------------------------------------------------------------
__global__ __launch_bounds__(256) void wcomb_kernel(
    const float* __restrict__ xpw, const float* __restrict__ dtw,
    __hip_bfloat16* __restrict__ wcb) {
  int gid = blockIdx.x * 256 + threadIdx.x;   // < 448*384
  int dd = gid / 384, k = gid % 384;
  float v = 0.f;
  if (dd < 384) {
#pragma unroll
    for (int j = 0; j < 12; ++j) v = fmaf(dtw[dd * 12 + j], xpw[j * 384 + k], v);
  } else if (dd < 416) {
    v = xpw[(dd - 372) * 384 + k];
  }
  wcb[gid] = __float2bfloat16(v);
}

// ---------------------------------------------------------------------------
// K1: [B,C,H,W] -> LayerNorm over C -> xn_bf16 [B*L, C]
// ---------------------------------------------------------------------------
__global__ __launch_bounds__(512) void ln_kernel(
    const float* __restrict__ x, const float* __restrict__ ln_w,
    const float* __restrict__ ln_b, __hip_bfloat16* __restrict__ xn) {
  __shared__ float xs[DIMC][WSP + 1];
  __shared__ float mu_s[WSP], rs_s[WSP];
  int bh = blockIdx.x;
  int b = bh >> 6, h = bh & 63;
  int tid = threadIdx.x;
  const float* xb = x + (size_t)b * DIMC * LSEQ + (size_t)h * WSP;
  for (int e = tid; e < DIMC * WSP; e += 512) {
    int c = e >> 6, w = e & 63;
    xs[c][w] = xb[(size_t)c * LSEQ + w];
  }
  __syncthreads();
  {
    int w = tid >> 3, p = tid & 7;
    float s = 0.f, s2 = 0.f;
#pragma unroll
    for (int i = 0; i < 24; ++i) {
      float v = xs[p * 24 + i][w];
      s += v; s2 = fmaf(v, v, s2);
    }
    s  += __shfl_xor(s, 1);  s2 += __shfl_xor(s2, 1);
    s  += __shfl_xor(s, 2);  s2 += __shfl_xor(s2, 2);
    s  += __shfl_xor(s, 4);  s2 += __shfl_xor(s2, 4);
    if (p == 0) {
      float mu = s * (1.f / DIMC);
      float var = s2 * (1.f / DIMC) - mu * mu;
      mu_s[w] = mu;
      rs_s[w] = rsqrtf(var + 1e-5f);
    }
  }
  __syncthreads();
  __hip_bfloat16* xo = xn + (size_t)(b * LSEQ + h * WSP) * DIMC;
  for (int e = tid; e < DIMC * WSP; e += 512) {
    int w = e / DIMC, c = e % DIMC;
    xo[(size_t)w * DIMC + c] =
        __float2bfloat16((xs[c][w] - mu_s[w]) * rs_s[w] * ln_w[c] + ln_b[c]);
  }
}

// ---------------------------------------------------------------------------
// bf16 MFMA GEMM: C[M,N] = A[M,K] @ B[N,K]^T   (both row-major [dim][K] bf16)
// EPI 1: per-batch residual + f32 store [B,C,L].
// EPI 2: bf16 out, guard ncol<Nreal.
// EPI 4: fused x_proj+dt epilogue:
//        ncol<384  -> dxpk[m][ncol] = pack(softplus(acc+bias[ncol]), xm[m][ncol])
//        384..415  -> dbcb[m][16 + ncol-384] (B then C)
// ---------------------------------------------------------------------------
template<int WM, int WN, int FM, int FN, int EPI>
__global__ __launch_bounds__(256) void gemm_bf16(
    const ushortT* __restrict__ A, const ushortT* __restrict__ B,
    void* __restrict__ Cv, void* __restrict__ Cv2,
    const ushortT* __restrict__ xm_aux, const float* __restrict__ bias384,
    const float* __restrict__ xres, int K, int Nreal, int ldc) {
  constexpr int BM = WM * FM * 16, BN = WN * FN * 16;
  __shared__ ushortT As[BM][72];
  __shared__ ushortT Bs[BN][72];
  int bm = blockIdx.x * BM, bn = blockIdx.y * BN;
  int tid = threadIdx.x, lane = tid & 63, w = tid >> 6;
  int wm = w / WN, wn = w % WN;
  int lm = lane & 15, lk = lane >> 4;
  const ushortT* Bb = B;
  size_t zoff = 0;
  if constexpr (EPI == 1) {
    size_t zb = blockIdx.z;
    Bb = B + zb * (size_t)LSEQ * K;
    zoff = zb * (size_t)DIMC * LSEQ;
  }
  f32x4 acc[FM][FN];
#pragma unroll
  for (int mi = 0; mi < FM; ++mi)
#pragma unroll
    for (int ni = 0; ni < FN; ++ni) acc[mi][ni] = (f32x4){0.f, 0.f, 0.f, 0.f};

  for (int k0 = 0; k0 < K; k0 += 64) {
    __syncthreads();
    for (int v = tid; v < BM * 8; v += 256) {
      int row = v >> 3, c8 = v & 7;
      *(uint4*)&As[row][c8 * 8] =
          *(const uint4*)(A + (size_t)(bm + row) * K + k0 + c8 * 8);
    }
    for (int v = tid; v < BN * 8; v += 256) {
      int row = v >> 3, c8 = v & 7;
      *(uint4*)&Bs[row][c8 * 8] =
          *(const uint4*)(Bb + (size_t)(bn + row) * K + k0 + c8 * 8);
    }
    __syncthreads();
#pragma unroll
    for (int ks = 0; ks < 2; ++ks) {
      short8 af[FM], bfr[FN];
#pragma unroll
      for (int mi = 0; mi < FM; ++mi)
        af[mi] = *(const short8*)&As[wm * FM * 16 + mi * 16 + lm][ks * 32 + lk * 8];
#pragma unroll
      for (int ni = 0; ni < FN; ++ni)
        bfr[ni] = *(const short8*)&Bs[wn * FN * 16 + ni * 16 + lm][ks * 32 + lk * 8];
#pragma unroll
      for (int mi = 0; mi < FM; ++mi)
#pragma unroll
        for (int ni = 0; ni < FN; ++ni)
          acc[mi][ni] = __builtin_amdgcn_mfma_f32_16x16x32_bf16(
              af[mi], bfr[ni], acc[mi][ni], 0, 0, 0);
    }
  }
#pragma unroll
  for (int mi = 0; mi < FM; ++mi) {
#pragma unroll
    for (int ni = 0; ni < FN; ++ni) {
      int ncol = bn + wn * FN * 16 + ni * 16 + lm;
#pragma unroll
      for (int r = 0; r < 4; ++r) {
        int m = bm + wm * FM * 16 + mi * 16 + lk * 4 + r;
        if constexpr (EPI == 1) {
          size_t aidx = zoff + (size_t)m * LSEQ + ncol;
          ((float*)Cv)[aidx] = xres[aidx] + acc[mi][ni][r];
        } else if constexpr (EPI == 2) {
          if (ncol < Nreal)
            ((__hip_bfloat16*)Cv)[(size_t)m * ldc + ncol] =
                __float2bfloat16(acc[mi][ni][r]);
        } else {  // EPI 4
          if (ncol < 384) {
            float dtr = acc[mi][ni][r] + bias384[ncol];
            float dt = dtr > 15.f ? dtr : __logf(1.f + __expf(dtr));
            float xmv = bf2f(xm_aux[(size_t)m * DINNER + ncol]);
            ((unsigned*)Cv)[(size_t)m * DINNER + ncol] = pkbf(dt, xmv);
          } else if (ncol < 416) {
            __hip_bfloat16 bv = __float2bfloat16(acc[mi][ni][r]);
            ((ushortT*)Cv2)[(size_t)m * 48 + 16 + (ncol - 384)] = *(ushortT*)&bv;
          }
        }
      }
    }
  }
}

// ---------------------------------------------------------------------------
// K3: causal depthwise conv (k=4) + bias + SiLU, 8 channels per thread
// ---------------------------------------------------------------------------
__global__ __launch_bounds__(256) void conv_silu_kernel(
    const __hip_bfloat16* __restrict__ xz, const float* __restrict__ conv_w,
    const float* __restrict__ conv_b, __hip_bfloat16* __restrict__ xmh) {
  int g8 = blockIdx.x * 256 + threadIdx.x;      // < NTOK*384/8
  int d8 = g8 % 48;                             // 8-channel group
  int tok = g8 / 48;
  int l = tok & (LSEQ - 1);
  int d0 = d8 * 8;
  const ushortT* base = (const ushortT*)xz + (size_t)tok * XZW + d0;
  uint4 r0, r1, r2, r3;
  r3 = *(const uint4*)(base);
  r2 = l >= 1 ? *(const uint4*)(base - XZW)     : (uint4){0, 0, 0, 0};
  r1 = l >= 2 ? *(const uint4*)(base - 2 * XZW) : (uint4){0, 0, 0, 0};
  r0 = l >= 3 ? *(const uint4*)(base - 3 * XZW) : (uint4){0, 0, 0, 0};
  float x0[8], x1[8], x2[8], x3[8];
  UNPK8(x0, 0, r0) UNPK8(x1, 0, r1) UNPK8(x2, 0, r2) UNPK8(x3, 0, r3)
  ushortT outv[8];
#pragma unroll
  for (int j = 0; j < 8; ++j) {
    const float4 w = *(const float4*)(conv_w + (d0 + j) * 4);
    float acc = conv_b[d0 + j];
    acc = fmaf(w.x, x0[j], acc);
    acc = fmaf(w.y, x1[j], acc);
    acc = fmaf(w.z, x2[j], acc);
    acc = fmaf(w.w, x3[j], acc);
    float s = acc / (1.f + __expf(-acc));
    __hip_bfloat16 sb = __float2bfloat16(s);
    outv[j] = *(ushortT*)&sb;
  }
  *(uint4*)((ushortT*)xmh + (size_t)tok * DINNER + d0) = *(uint4*)outv;
}

// ---------------------------------------------------------------------------
// K6a: chunk-local scan (LC=16): h_end from 0 + decay product -> packed u32
// ---------------------------------------------------------------------------
__global__ __launch_bounds__(384) void scan_part1(
    const unsigned* __restrict__ dxpk, const ushortT* __restrict__ dbc,
    const float* __restrict__ A_log, unsigned* __restrict__ hpk) {
  __shared__ ushortT dbc_s[16 * 48];
  int d = threadIdx.x, c = blockIdx.x, b = blockIdx.y;
  size_t rowbase = (size_t)b * LSEQ + (size_t)c * LC4;
  if (d < 96) {
    int row = d / 6, q = d % 6;
    ((uint4*)dbc_s)[d] = ((const uint4*)(dbc + (rowbase + row) * 48))[q];
  }
  float Ac2[16];
#pragma unroll
  for (int q = 0; q < 4; ++q) {
    float4 t4 = *(const float4*)(A_log + d * 16 + q * 4);
    Ac2[q * 4 + 0] = -__expf(t4.x) * 1.44269504f;
    Ac2[q * 4 + 1] = -__expf(t4.y) * 1.44269504f;
    Ac2[q * 4 + 2] = -__expf(t4.z) * 1.44269504f;
    Ac2[q * 4 + 3] = -__expf(t4.w) * 1.44269504f;
  }
  float h[16];
#pragma unroll
  for (int n = 0; n < 16; ++n) h[n] = 0.f;
  float sdt = 0.f;
  const unsigned* pkp = dxpk + rowbase * DINNER + d;
  __syncthreads();
#pragma unroll
  for (int t0 = 0; t0 < 16; t0 += 4) {
    unsigned pk[4];
#pragma unroll
    for (int j = 0; j < 4; ++j) pk[j] = pkp[(t0 + j) * DINNER];
#pragma unroll
    for (int j = 0; j < 4; ++j) {
      int t = t0 + j;
      float dtt = bflo(pk[j]), xmv = bfhi(pk[j]);
      sdt += dtt;
      float dx = dtt * xmv;
      const char* bb = (const char*)dbc_s + t * 96;
      uint4 B0 = *(const uint4*)(bb + 32);
      uint4 B1 = *(const uint4*)(bb + 48);
      float Bv[16];
      UNPK8(Bv, 0, B0)
      UNPK8(Bv, 8, B1)
#pragma unroll
      for (int n = 0; n < 16; ++n) {
        float a = __builtin_amdgcn_exp2f(dtt * Ac2[n]);
        h[n] = fmaf(h[n], a, dx * Bv[n]);
      }
    }
  }
  unsigned up[16];
#pragma unroll
  for (int n = 0; n < 16; ++n)
    up[n] = pkbf(h[n], __builtin_amdgcn_exp2f(Ac2[n] * sdt));
  uint4* hp4 = (uint4*)(hpk + (((size_t)b * NCH4 + c) * DINNER + d) * 16);
#pragma unroll
  for (int q = 0; q < 4; ++q) hp4[q] = *(uint4*)&up[q * 4];
}

// ---------------------------------------------------------------------------
// K6b: sequential chunk-boundary propagation
// ---------------------------------------------------------------------------
__global__ __launch_bounds__(256) void scan_part2(
    const unsigned* __restrict__ hpk, ushortT* __restrict__ hinb) {
  int e = blockIdx.x * 256 + threadIdx.x;   // [0, 6144)
  int b = blockIdx.y;
  float H = 0.f;
  size_t base = (size_t)b * NCH4 * (DINNER * DSTATE) + e;
#pragma unroll 16
  for (int c = 0; c < NCH4; ++c) {
    size_t idx = base + (size_t)c * (DINNER * DSTATE);
    unsigned w = hpk[idx];
    __hip_bfloat16 hb = __float2bfloat16(H);
    hinb[idx] = *(ushortT*)&hb;
    H = fmaf(bfhi(w), H, bflo(w));   // pa = hi, h_end = lo
  }
}

// ---------------------------------------------------------------------------
// K6c: seeded chunk scan -> y (in-lane C-dot) + D-skip + SiLU gate -> ybuf
// ---------------------------------------------------------------------------
__global__ __launch_bounds__(384) void scan_part3(
    const unsigned* __restrict__ dxpk, const ushortT* __restrict__ dbc,
    const __hip_bfloat16* __restrict__ xz, const float* __restrict__ A_log,
    const float* __restrict__ Dvec, const ushortT* __restrict__ hinb,
    __hip_bfloat16* __restrict__ ybuf) {
  __shared__ ushortT dbc_s[16 * 48];
  int d = threadIdx.x, c = blockIdx.x, b = blockIdx.y;
  size_t rowbase = (size_t)b * LSEQ + (size_t)c * LC4;
  if (d < 96) {
    int row = d / 6, q = d % 6;
    ((uint4*)dbc_s)[d] = ((const uint4*)(dbc + (rowbase + row) * 48))[q];
  }
  float Ac2[16];
#pragma unroll
  for (int q = 0; q < 4; ++q) {
    float4 t4 = *(const float4*)(A_log + d * 16 + q * 4);
    Ac2[q * 4 + 0] = -__expf(t4.x) * 1.44269504f;
    Ac2[q * 4 + 1] = -__expf(t4.y) * 1.44269504f;
    Ac2[q * 4 + 2] = -__expf(t4.z) * 1.44269504f;
    Ac2[q * 4 + 3] = -__expf(t4.w) * 1.44269504f;
  }
  float h[16];
  {
    const uint4* hp = (const uint4*)(hinb + (((size_t)b * NCH4 + c) * DINNER + d) * 16);
    uint4 h0 = hp[0], h1 = hp[1];
    UNPK8(h, 0, h0)
    UNPK8(h, 8, h1)
  }
  float Dd = Dvec[d];
  const unsigned* pkp = dxpk + rowbase * DINNER + d;
  const ushortT* zp = (const ushortT*)xz + rowbase * XZW + DINNER + d;
  __hip_bfloat16* yp = ybuf + rowbase * DINNER + d;
  __syncthreads();
#pragma unroll
  for (int t0 = 0; t0 < 16; t0 += 4) {
    unsigned pk[4];
    ushortT zv4[4];
#pragma unroll
    for (int j = 0; j < 4; ++j) {
      pk[j] = pkp[(t0 + j) * DINNER];
      zv4[j] = zp[(t0 + j) * XZW];
    }
#pragma unroll
    for (int j = 0; j < 4; ++j) {
      int t = t0 + j;
      float dtt = bflo(pk[j]), xmv = bfhi(pk[j]);
      float dx = dtt * xmv;
      const char* bb = (const char*)dbc_s + t * 96;
      uint4 B0 = *(const uint4*)(bb + 32);
      uint4 B1 = *(const uint4*)(bb + 48);
      uint4 C0 = *(const uint4*)(bb + 64);
      uint4 C1 = *(const uint4*)(bb + 80);
      float Bv[16], Cw[16];
      UNPK8(Bv, 0, B0)
      UNPK8(Bv, 8, B1)
      UNPK8(Cw, 0, C0)
      UNPK8(Cw, 8, C1)
      float y0 = 0.f, y1 = 0.f, y2 = 0.f, y3 = 0.f;
#pragma unroll
      for (int n = 0; n < 16; n += 4) {
        float a0 = __builtin_amdgcn_exp2f(dtt * Ac2[n + 0]);
        float a1 = __builtin_amdgcn_exp2f(dtt * Ac2[n + 1]);
        float a2 = __builtin_amdgcn_exp2f(dtt * Ac2[n + 2]);
        float a3 = __builtin_amdgcn_exp2f(dtt * Ac2[n + 3]);
        h[n + 0] = fmaf(h[n + 0], a0, dx * Bv[n + 0]);
        h[n + 1] = fmaf(h[n + 1], a1, dx * Bv[n + 1]);
        h[n + 2] = fmaf(h[n + 2], a2, dx * Bv[n + 2]);
        h[n + 3] = fmaf(h[n + 3], a3, dx * Bv[n + 3]);
        y0 = fmaf(h[n + 0], Cw[n + 0], y0);
        y1 = fmaf(h[n + 1], Cw[n + 1], y1);
        y2 = fmaf(h[n + 2], Cw[n + 2], y2);
        y3 = fmaf(h[n + 3], Cw[n + 3], y3);
      }
      float yv = fmaf(xmv, Dd, (y0 + y1) + (y2 + y3));
      float zv = bf2f(zv4[j]);
      float gt = zv * __builtin_amdgcn_rcpf(
          1.f + __builtin_amdgcn_exp2f(zv * -1.44269504f));
      yp[(size_t)t * DINNER] = __float2bfloat16(yv * gt);
    }
  }
}

// ---------------------------------------------------------------------------
extern "C" void kernel_launch(void* const* d_in, const int* in_sizes, int n_in,
                              void* d_out, int out_size, void* d_ws, size_t ws_size,
                              hipStream_t stream) {
  const float* x        = (const float*)d_in[0];
  const float* ln_w     = (const float*)d_in[1];
  const float* ln_b     = (const float*)d_in[2];
  const float* in_proj  = (const float*)d_in[3];   // [768,192]
  const float* conv_w   = (const float*)d_in[4];   // [384,4]
  const float* conv_b   = (const float*)d_in[5];   // [384]
  const float* x_proj   = (const float*)d_in[6];   // [44,384]
  const float* dt_w     = (const float*)d_in[7];   // [384,12]
  const float* dt_b     = (const float*)d_in[8];   // [384]
  const float* A_log    = (const float*)d_in[9];   // [384,16]
  const float* Dvec     = (const float*)d_in[10];  // [384]
  const float* out_proj = (const float*)d_in[11];  // [192,384]
  float* out = (float*)d_out;

  // workspace layout (float units), ~122 MB
  float* ws = (float*)d_ws;
  __hip_bfloat16* xzb  = (__hip_bfloat16*)ws;                    // [16384][768] bf16
  __hip_bfloat16* xmh  = (__hip_bfloat16*)(ws + 6291456);        // [16384][384] bf16
  ushortT*        dbcb = (ushortT*)(ws + 9437184);               // [16384][48] bf16
  unsigned*       dxpk = (unsigned*)(ws + 9830400);              // [16384][384] u32 (dt,xm)
  unsigned*       hpk  = (unsigned*)(ws + 16121856);             // [4][256][384][16] u32
  ushortT*        hinb = (ushortT*)(ws + 22413312);              // same shape bf16
  __hip_bfloat16* ybuf = (__hip_bfloat16*)(ws + 25559040);       // [16384][384] bf16
  __hip_bfloat16* xnbf = (__hip_bfloat16*)(ws + 28704768);       // [16384][192] bf16
  __hip_bfloat16* wbf  = (__hip_bfloat16*)(ws + 30277632);       // 221184 bf16
  __hip_bfloat16* wcb  = (__hip_bfloat16*)(ws + 30388224);       // 172032 bf16

  const ushortT* win  = (const ushortT*)wbf;             // [768][192]
  const ushortT* wout = (const ushortT*)(wbf + 147456);  // [192][384]

  wcvt_kernel<<<864, 256, 0, stream>>>(in_proj, out_proj, wbf);
  wcomb_kernel<<<672, 256, 0, stream>>>(x_proj, dt_w, wcb);

  ln_kernel<<<BSZ * HSP, 512, 0, stream>>>(x, ln_w, ln_b, xnbf);

  // in_proj: [16384,192] x [768,192]^T -> xzb bf16 [16384,768]  (BM=128,BN=128)
  gemm_bf16<2, 2, 4, 4, 2><<<dim3(NTOK / 128, XZW / 128), 256, 0, stream>>>(
      (const ushortT*)xnbf, win, xzb, nullptr, nullptr, nullptr, nullptr,
      DIMC, XZW, XZW);

  conv_silu_kernel<<<(NTOK * DINNER / 8) / 256, 256, 0, stream>>>(
      xzb, conv_w, conv_b, xmh);

  // fused x_proj + dt_proj + softplus + pack: [16384,384] x [448,384]^T
  gemm_bf16<2, 2, 4, 2, 4><<<dim3(NTOK / 128, NXP / 64), 256, 0, stream>>>(
      (const ushortT*)xmh, (const ushortT*)wcb, dxpk, dbcb,
      (const ushortT*)xmh, dt_b, nullptr, DINNER, NXP, 0);

  scan_part1<<<dim3(NCH4, BSZ), 384, 0, stream>>>(dxpk, dbcb, A_log, hpk);
  scan_part2<<<dim3(DINNER * DSTATE / 256, BSZ), 256, 0, stream>>>(hpk, hinb);
  scan_part3<<<dim3(NCH4, BSZ), 384, 0, stream>>>(
      dxpk, dbcb, xzb, A_log, Dvec, hinb, ybuf);

  // out_proj: A=w_out[192][384], B=ybuf[b][4096][384] -> out[b][192][4096] + residual
  gemm_bf16<2, 2, 2, 4, 1><<<dim3(DIMC / 64, LSEQ / 128, BSZ), 256, 0, stream>>>(
      wout, (const ushortT*)ybuf, out, nullptr, nullptr, nullptr, x,
      DINNER, LSEQ, LSEQ);
}